// Round 8
// baseline (180.323 us; speedup 1.0000x reference)
//
#include <hip/hip_runtime.h>
#include <math.h>

// Problem constants
#define Bn    64
#define Cn    3
#define IMG   224
#define PLANE (IMG*IMG)      // 50176
#define C1    6
#define P1    110            // conv1(220) + maxpool2 -> 110
#define P2    106            // conv2 output spatial
#define NVALID (P2*P2)       // 11236
#define Hh    32
#define Ww    64
#define UPR   10
#define UPT   10
#define Hg    (Hh*UPR)       // 320
#define Wg    (Ww*UPT)       // 640
#define POOLED_SIZE (Bn*Cn*Hh*Ww)   // 393216
#define RPB   4              // pooled rows per chunk (1 per wave, 4 waves)
#define NCHUNK ((P1 + RPB - 1) / RPB)   // 28
#define PCHUNK (NCHUNK * RPB)           // 112 per-wave partial slots
#define PSTRIDE 152          // padded 150-float partial slot

typedef unsigned short u16;
typedef unsigned int   u32;
typedef float v2f __attribute__((ext_vector_type(2)));
typedef u32   v4u __attribute__((ext_vector_type(4), aligned(8)));

// workspace: partials (B*112*152 f32) | wt (B*2 f32) | x4b (B*224*224*4 bf16)
#define PART_FLOATS ((size_t)Bn * PCHUNK * PSTRIDE)     // 1,089,536
#define X4B_U16     ((size_t)Bn * PLANE * 4)
#define WS_NEEDED   ((PART_FLOATS + Bn * 2) * 4 + X4B_U16 * 2)

__device__ __forceinline__ u16 f2bf(float f) {
    union { u32 u; float f; } c; c.f = f;
    u32 r = c.u + 0x7fffu + ((c.u >> 16) & 1u);   // RNE
    return (u16)(r >> 16);
}
__device__ __forceinline__ float bf2f(u16 v) {
    union { u32 u; float f; } c; c.u = ((u32)v) << 16;
    return c.f;
}
__device__ __forceinline__ float bflo(u32 u) {
    union { u32 u; float f; } c; c.u = u << 16;           return c.f;
}
__device__ __forceinline__ float bfhi(u32 u) {
    union { u32 u; float f; } c; c.u = u & 0xffff0000u;   return c.f;
}

// 7 overlapping pairs P[j] = (r[j], r[j+1]) from an 8-float LDS row segment.
__device__ __forceinline__ void load_pairs(v2f* P, const float* rp) {
    const float4 a = *(const float4*)rp;
    const float4 c = *(const float4*)(rp + 4);
    P[0] = (v2f){a.x, a.y};
    P[1] = (v2f){a.y, a.z};
    P[2] = (v2f){a.z, a.w};
    P[3] = (v2f){a.w, c.x};
    P[4] = (v2f){c.x, c.y};
    P[5] = (v2f){c.y, c.z};
    P[6] = (v2f){c.z, c.w};
}

// -------------------------------------------------------------------------
// K1: fused conv1 (all 6 OCs, packed-fp32 v_pk_fma) + maxpool2 + bf16-NHWC4
// repack + shuffle window sums -> per-WAVE partials in ws (no psum LDS ->
// xs-only 31.5 KB -> 5 blocks/CU). Grid (14,64), each block does chunks
// 2q, 2q+1 (896 blocks: fewer than one co-resident round).
// -------------------------------------------------------------------------
__global__ __launch_bounds__(256) void k1_fused(
    const float* __restrict__ x,      // (B,3,224,224)
    const float* __restrict__ w1,     // (6,3,5,5)
    const float* __restrict__ b1,     // (6,)
    float* __restrict__ partial,      // (B,112,PSTRIDE) per-wave
    u16* __restrict__ x4b,            // (B,224,224,4) bf16 out
    int do_pack)
{
    __shared__ __attribute__((aligned(16))) float xs[3][12][224];  // 32256 B

    const int b    = blockIdx.y;
    const int tid  = threadIdx.x;
    const int wid  = tid >> 6;
    const int lane = tid & 63;

    const float* xb = x + (size_t)b * (Cn * PLANE);

    for (int half = 0; half < 2; ++half) {
        const int chunk = 2 * blockIdx.x + half;
        const int y0 = chunk * RPB;
        const int gybase = 2 * y0;

        // stage 12 input rows x 3 ic, coalesced float4
        for (int i = tid; i < 3 * 12 * 56; i += 256) {
            const int ic  = i / (12 * 56);
            const int rem = i - ic * (12 * 56);
            const int r   = rem / 56;
            const int c4  = rem - r * 56;
            const int gy  = gybase + r;
            if (gy < IMG)
                *(float4*)(&xs[ic][r][c4 * 4]) =
                    *(const float4*)(xb + ic * PLANE + gy * IMG + c4 * 4);
        }
        __syncthreads();

        // bf16 NHWC4 pack of this chunk's 8 owned rows (28 chunks x 8 = 224)
        if (do_pack) {
            u16* ob = x4b + (size_t)b * PLANE * 4;
            for (int i = tid; i < 8 * IMG; i += 256) {
                const int r   = i / IMG;
                const int col = i - r * IMG;
                const int gy  = gybase + r;
                ushort4 v;
                v.x = f2bf(xs[0][r][col]);
                v.y = f2bf(xs[1][r][col]);
                v.z = f2bf(xs[2][r][col]);
                v.w = 0;
                *(ushort4*)(ob + ((size_t)gy * IMG + col) * 4) = v;
            }
        }

        const int y = y0 + wid;
        const bool rowvalid = (y < P1);
        const bool active = (lane < 55) && rowvalid;

        float pp0[C1], pp1[C1];
        if (active) {
            v2f accT01[C1], accT23[C1], accB01[C1], accB23[C1];
            #pragma unroll
            for (int oc = 0; oc < C1; ++oc) {
                const float bv = b1[oc];
                const v2f bvv = (v2f){bv, bv};
                accT01[oc] = bvv; accT23[oc] = bvv;
                accB01[oc] = bvv; accB23[oc] = bvv;
            }

            #pragma unroll
            for (int ic = 0; ic < 3; ++ic) {
                v2f Pa[7], Pb[7];
                load_pairs(Pa, &xs[ic][2 * wid][4 * lane]);
                load_pairs(Pb, &xs[ic][2 * wid + 1][4 * lane]);
                #pragma unroll
                for (int ky = 0; ky < 5; ++ky) {
                    const v2f* Pt = (ky & 1) ? Pb : Pa;   // row 2y+ky
                    const v2f* Po = (ky & 1) ? Pa : Pb;   // row 2y+ky+1
                    #pragma unroll
                    for (int oc = 0; oc < C1; ++oc) {
                        const float* wrow = w1 + ((oc * 3 + ic) * 25 + ky * 5);
                        #pragma unroll
                        for (int kx = 0; kx < 5; ++kx) {
                            const float wv = wrow[kx];     // uniform s_load
                            const v2f wvv = (v2f){wv, wv};
                            accT01[oc] += Pt[kx]     * wvv;  // v_pk_fma_f32
                            accT23[oc] += Pt[kx + 2] * wvv;
                            accB01[oc] += Po[kx]     * wvv;
                            accB23[oc] += Po[kx + 2] * wvv;
                        }
                    }
                    if (ky < 4)
                        load_pairs((ky & 1) ? Pb : Pa,
                                   &xs[ic][2 * wid + ky + 2][4 * lane]);
                }
            }

            #pragma unroll
            for (int oc = 0; oc < C1; ++oc) {
                pp0[oc] = fmaxf(fmaxf(accT01[oc].x, accT01[oc].y),
                                fmaxf(accB01[oc].x, accB01[oc].y));
                pp1[oc] = fmaxf(fmaxf(accT23[oc].x, accT23[oc].y),
                                fmaxf(accB23[oc].x, accB23[oc].y));
            }
        } else {
            #pragma unroll
            for (int oc = 0; oc < C1; ++oc) { pp0[oc] = 0.0f; pp1[oc] = 0.0f; }
        }

        // Wave-level windowed row sums -> per-wave global partial slot.
        float* dst = partial + ((size_t)b * PCHUNK + chunk * RPB + wid) * PSTRIDE;
        #pragma unroll
        for (int oc = 0; oc < C1; ++oc) {
            float s = pp0[oc] + pp1[oc];
            #pragma unroll
            for (int off = 32; off > 0; off >>= 1) s += __shfl_xor(s, off, 64);
            const float c0   = __shfl(pp0[oc], 0, 64);
            const float c1   = __shfl(pp1[oc], 0, 64);
            const float c2   = __shfl(pp0[oc], 1, 64);
            const float c3   = __shfl(pp1[oc], 1, 64);
            const float c106 = __shfl(pp0[oc], 53, 64);
            const float c107 = __shfl(pp1[oc], 53, 64);
            const float c108 = __shfl(pp0[oc], 54, 64);
            const float c109 = __shfl(pp1[oc], 54, 64);
            const float w0v = s - (c106 + c107 + c108 + c109);
            const float w1v = s - c0 - (c107 + c108 + c109);
            const float w2v = s - (c0 + c1) - (c108 + c109);
            const float w3v = s - (c0 + c1 + c2) - c109;
            const float w4v = s - (c0 + c1 + c2 + c3);
            if (lane < 25) {
                const int ky = lane / 5;
                const int kx = lane % 5;
                float wv = w0v;
                wv = (kx == 1) ? w1v : wv;
                wv = (kx == 2) ? w2v : wv;
                wv = (kx == 3) ? w3v : wv;
                wv = (kx == 4) ? w4v : wv;
                const bool valid = rowvalid && ((unsigned)(y - ky) <= 105u);
                dst[oc * 25 + lane] = valid ? wv : 0.0f;
            }
        }
        __syncthreads();   // xs reuse guard for next half's staging
    }
}

// -------------------------------------------------------------------------
// K2: reduce 112 per-wave partials -> wsum_b; feat = b2 + (W2.wsum)/11236;
// fc1+relu ; fc2+sigmoid*5. One block (256 threads) per batch element.
// -------------------------------------------------------------------------
__global__ __launch_bounds__(256) void k2_head(
    const float* __restrict__ partial, const float* __restrict__ w2,
    const float* __restrict__ b2, const float* __restrict__ fc1w,
    const float* __restrict__ fc1b, const float* __restrict__ fc2w,
    const float* __restrict__ fc2b, float* __restrict__ wt_ws,
    float* __restrict__ out)
{
    const int b = blockIdx.x;
    const int tid = threadIdx.x;
    __shared__ float wsb[150];
    __shared__ float sfeat[16];
    __shared__ float sh[8];

    if (tid < 150) {
        const float* p = partial + (size_t)b * PCHUNK * PSTRIDE + tid;
        float s = 0.0f;
        #pragma unroll 8
        for (int c = 0; c < PCHUNK; ++c) s += p[c * PSTRIDE];
        wsb[tid] = s;
    }
    __syncthreads();
    if (tid < 16) {
        float s = 0.0f;
        for (int j = 0; j < 150; ++j) s += w2[tid * 150 + j] * wsb[j];
        sfeat[tid] = b2[tid] + s * (1.0f / (float)NVALID);
    }
    __syncthreads();
    if (tid < 8) {
        float s = fc1b[tid];
        #pragma unroll
        for (int j = 0; j < 16; ++j) s += fc1w[tid * 16 + j] * sfeat[j];
        sh[tid] = fmaxf(s, 0.0f);
    }
    __syncthreads();
    if (tid < 2) {
        float s = fc2b[tid];
        #pragma unroll
        for (int j = 0; j < 8; ++j) s += fc2w[tid * 8 + j] * sh[j];
        float sig = (s >= 0.0f) ? (1.0f / (1.0f + expf(-s)))
                                : (expf(s) / (1.0f + expf(s)));
        const float wgt = 5.0f * sig;
        wt_ws[b * 2 + tid] = wgt;
        out[POOLED_SIZE + b * 2 + tid] = wgt;
    }
}

// -------------------------------------------------------------------------
// Clamp-coordinate sampling (equivalent to corner-clamp border mode).
// -------------------------------------------------------------------------
__device__ __forceinline__ void sample_coords(
    float gxn, float gyn, int& x0, int& y0, float& wx, float& wy)
{
    float ix = ((gxn + 1.0f) * (float)IMG - 1.0f) * 0.5f;
    float iy = ((gyn + 1.0f) * (float)IMG - 1.0f) * 0.5f;
    ix = fminf(fmaxf(ix, 0.0f), (float)(IMG - 1));
    iy = fminf(fmaxf(iy, 0.0f), (float)(IMG - 1));
    x0 = (int)ix; if (x0 > IMG - 2) x0 = IMG - 2;
    y0 = (int)iy; if (y0 > IMG - 2) y0 = IMG - 2;
    wx = ix - (float)x0;
    wy = iy - (float)y0;
}

// -------------------------------------------------------------------------
// K3 (bf16 NHWC4): log-polar grid sample + 10x10 avg pool.
// XCD-affinity swizzle (R5): b = (L&7) + 8*(L>>8).
// Per sample: 2 x 16B row loads (dwordx4, 8B-aligned legal) instead of
// 4 x 8B -> half the L1 transactions (the R7 bottleneck).
// -------------------------------------------------------------------------
__global__ __launch_bounds__(640) void k3_sample_pool_bf16(
    const u16* __restrict__ x4b,      // (B,224,224,4) bf16
    const float* __restrict__ ltp,
    const float* __restrict__ wt,
    float* __restrict__ out)
{
    __shared__ float part[3 * Wg];

    const int L = blockIdx.x;         // 0..2047
    const int q = L >> 3;             // 0..255
    const int h = q & 31;
    const int b = (L & 7) + 8 * (q >> 5);
    const int tid = threadIdx.x;

    const float w0 = wt[b * 2 + 0];
    const float w1 = wt[b * 2 + 1];
    const float l0 = ltp[b * 2 + 0];
    const float l1 = ltp[b * 2 + 1];
    const float start = logf(0.01f * w0);
    const float stop  = logf(0.6f  * w1);
    const float dr = stop - start;

    const float angle = 6.283185307179586f * (float)tid / (float)Wg;
    const float sn = sinf(angle);
    const float cs = cosf(angle);

    const u32* xb4 = (const u32*)(x4b + (size_t)b * PLANE * 4);

    const float ratio = expf(dr * (1.0f / (float)(Hg - 1)));
    float r = expf(start + dr * ((float)(h * UPR) / (float)(Hg - 1)));

    float acc0 = 0.0f, acc1 = 0.0f, acc2 = 0.0f;
    #pragma unroll
    for (int i = 0; i < UPR; ++i) {
        int x0, y0; float wx, wy;
        sample_coords(r * sn + l0, r * cs + l1, x0, y0, wx, wy);
        r *= ratio;

        const u32* base = xb4 + (size_t)(y0 * IMG + x0) * 2;
        const v4u r0 = *(const v4u*)(base);            // pixels x0,x1 @ y0
        const v4u r1 = *(const v4u*)(base + IMG * 2);  // pixels x0,x1 @ y0+1

        const float wx0 = 1.0f - wx, wy0 = 1.0f - wy;
        const float w00 = wx0 * wy0, w01 = wx * wy0;
        const float w10 = wx0 * wy,  w11 = wx * wy;

        acc0 += w00*bflo(r0.x) + w01*bflo(r0.z) + w10*bflo(r1.x) + w11*bflo(r1.z);
        acc1 += w00*bfhi(r0.x) + w01*bfhi(r0.z) + w10*bfhi(r1.x) + w11*bfhi(r1.z);
        acc2 += w00*bflo(r0.y) + w01*bflo(r0.w) + w10*bflo(r1.y) + w11*bflo(r1.w);
    }
    part[0 * Wg + tid] = acc0;
    part[1 * Wg + tid] = acc1;
    part[2 * Wg + tid] = acc2;
    __syncthreads();

    if (tid < Cn * Ww) {
        const int c = tid / Ww;
        const int w = tid % Ww;
        const float* p = part + c * Wg + w * UPT;
        float s = 0.0f;
        #pragma unroll
        for (int j = 0; j < UPT; ++j) s += p[j];
        out[(((size_t)b * Cn + c) * Hh + h) * Ww + w] = s * (1.0f / (UPR * UPT));
    }
}

// -------------------------------------------------------------------------
// K3 fallback (NCHW fp32 scalar gathers) — only if ws too small for x4b.
// -------------------------------------------------------------------------
__global__ __launch_bounds__(640) void k3_sample_pool_nchw(
    const float* __restrict__ x, const float* __restrict__ ltp,
    const float* __restrict__ wt, float* __restrict__ out)
{
    __shared__ float part[3 * Wg];
    const int L = blockIdx.x;
    const int q = L >> 3;
    const int h = q & 31;
    const int b = (L & 7) + 8 * (q >> 5);
    const int tid = threadIdx.x;

    const float w0 = wt[b * 2 + 0];
    const float w1 = wt[b * 2 + 1];
    const float l0 = ltp[b * 2 + 0];
    const float l1 = ltp[b * 2 + 1];
    const float start = logf(0.01f * w0);
    const float stop  = logf(0.6f  * w1);
    const float dr = stop - start;
    const float angle = 6.283185307179586f * (float)tid / (float)Wg;
    const float sn = sinf(angle);
    const float cs = cosf(angle);
    const float* xb = x + (size_t)b * Cn * PLANE;

    const float ratio = expf(dr * (1.0f / (float)(Hg - 1)));
    float r = expf(start + dr * ((float)(h * UPR) / (float)(Hg - 1)));

    float acc0 = 0.0f, acc1 = 0.0f, acc2 = 0.0f;
    #pragma unroll
    for (int i = 0; i < UPR; ++i) {
        int x0, y0; float wx, wy;
        sample_coords(r * sn + l0, r * cs + l1, x0, y0, wx, wy);
        r *= ratio;
        const float wx0 = 1.0f - wx, wy0 = 1.0f - wy;
        const float w00 = wx0 * wy0, w01 = wx * wy0;
        const float w10 = wx0 * wy,  w11 = wx * wy;
        const int o00 = y0 * IMG + x0;
        acc0 += w00*xb[o00] + w01*xb[o00+1] + w10*xb[o00+IMG] + w11*xb[o00+IMG+1];
        const float* x1p = xb + PLANE;
        acc1 += w00*x1p[o00] + w01*x1p[o00+1] + w10*x1p[o00+IMG] + w11*x1p[o00+IMG+1];
        const float* x2p = xb + 2 * PLANE;
        acc2 += w00*x2p[o00] + w01*x2p[o00+1] + w10*x2p[o00+IMG] + w11*x2p[o00+IMG+1];
    }
    part[0 * Wg + tid] = acc0;
    part[1 * Wg + tid] = acc1;
    part[2 * Wg + tid] = acc2;
    __syncthreads();

    if (tid < Cn * Ww) {
        const int c = tid / Ww;
        const int w = tid % Ww;
        const float* p = part + c * Wg + w * UPT;
        float s = 0.0f;
        #pragma unroll
        for (int j = 0; j < UPT; ++j) s += p[j];
        out[(((size_t)b * Cn + c) * Hh + h) * Ww + w] = s * (1.0f / (UPR * UPT));
    }
}

// -------------------------------------------------------------------------
extern "C" void kernel_launch(void* const* d_in, const int* in_sizes, int n_in,
                              void* d_out, int out_size, void* d_ws, size_t ws_size,
                              hipStream_t stream) {
    const float* x       = (const float*)d_in[0];
    const float* ltp     = (const float*)d_in[1];
    const float* conv1_w = (const float*)d_in[2];
    const float* conv1_b = (const float*)d_in[3];
    const float* conv2_w = (const float*)d_in[4];
    const float* conv2_b = (const float*)d_in[5];
    const float* fc1_w   = (const float*)d_in[6];
    const float* fc1_b   = (const float*)d_in[7];
    const float* fc2_w   = (const float*)d_in[8];
    const float* fc2_b   = (const float*)d_in[9];
    float* out = (float*)d_out;

    const int do_pack = (ws_size >= WS_NEEDED) ? 1 : 0;

    float* part_ws = (float*)d_ws;                // B*112*PSTRIDE
    float* wt_ws   = part_ws + PART_FLOATS;       // B*2
    u16*   x4b     = (u16*)(wt_ws + Bn * 2);      // 8B-aligned

    k1_fused<<<dim3(NCHUNK / 2, Bn), dim3(256), 0, stream>>>(
        x, conv1_w, conv1_b, part_ws, x4b, do_pack);
    k2_head<<<dim3(Bn), dim3(256), 0, stream>>>(part_ws, conv2_w, conv2_b,
                                                fc1_w, fc1_b, fc2_w, fc2_b,
                                                wt_ws, out);
    if (do_pack)
        k3_sample_pool_bf16<<<dim3(Hh * Bn), dim3(Wg), 0, stream>>>(x4b, ltp, wt_ws, out);
    else
        k3_sample_pool_nchw<<<dim3(Hh * Bn), dim3(Wg), 0, stream>>>(x, ltp, wt_ws, out);
}